// Round 10
// baseline (318.424 us; speedup 1.0000x reference)
//
#include <hip/hip_runtime.h>
#include <hip/hip_bf16.h>
#include <math.h>

// Problem constants
#define Bq  2
#define Sq  2048
#define Hq  1024
#define Nq  16
#define HNq 64
#define Mq  (Bq*Sq)        // 4096 rows
#define H3q (3*Hq)         // 3072

#define LOG2E 1.44269504088896340736f

typedef __attribute__((ext_vector_type(8))) short           short8;
typedef __attribute__((ext_vector_type(4))) short           short4s;
typedef __attribute__((ext_vector_type(8))) unsigned short  ushortx8;
typedef __attribute__((ext_vector_type(4))) unsigned short  ushortx4;
typedef __attribute__((ext_vector_type(4))) float           floatx4;

__device__ __forceinline__ unsigned short f2bf(float f) {
    union { float f; unsigned int u; } x; x.f = f;
    unsigned int r = (x.u + 0x7fffu + ((x.u >> 16) & 1u)) >> 16;
    return (unsigned short)r;
}

// packed fp32x2 -> bf16x2 (v_cvt_pk_bf16_f32 on gfx950); a in low 16 bits
__device__ __forceinline__ unsigned int pkbf(float a, float b) {
    float2 t; t.x = a; t.y = b;
    __hip_bfloat162 h = __float22bfloat162_rn(t);
    union { __hip_bfloat162 h; unsigned int u; } c; c.h = h;
    return c.u;
}

__device__ __forceinline__ float bf2f(unsigned short v) {
    union { unsigned int u; float f; } x; x.u = (unsigned int)v << 16;
    return x.f;
}

// async global->LDS, 16B per lane; LDS dest = wave-uniform base + lane*16
__device__ __forceinline__ void gload16(const unsigned short* g, unsigned short* l) {
    __builtin_amdgcn_global_load_lds(
        (__attribute__((address_space(1))) void*)(unsigned long long)(g),
        (__attribute__((address_space(3))) void*)(unsigned int)(unsigned long long)(l),
        16, 0, 0);
}

// LDS bank swizzle: granule' = granule ^ swz(row mod 16); 2-way max conflict
__device__ __forceinline__ int swz(int r) { return (r ^ (r >> 2)) & 3; }

// ---------------------------------------------------------------------------
// Fused fp32 -> bf16 cast for hidden | W_qkv | W_out (contiguous bf16 dst)
// ---------------------------------------------------------------------------
#define N_HID ((size_t)Mq * Hq)          // 4194304
#define N_HW  (N_HID + (size_t)H3q * Hq) // 7340032
#define N_ALL (N_HW + (size_t)Hq * Hq)   // 8388608

__global__ __launch_bounds__(256) void cvt_all(
    const float* __restrict__ hidden, const float* __restrict__ wqkv,
    const float* __restrict__ wout, unsigned short* __restrict__ dst)
{
    size_t i = ((size_t)blockIdx.x * 256 + threadIdx.x) * 8;
    const float* src;
    if (i < N_HID)      src = hidden + i;
    else if (i < N_HW)  src = wqkv + (i - N_HID);
    else                src = wout + (i - N_HW);
    float4 a = *(const float4*)(src);
    float4 b = *(const float4*)(src + 4);
    union { unsigned int u[4]; ushortx8 s; } o;
    o.u[0] = pkbf(a.x, a.y); o.u[1] = pkbf(a.z, a.w);
    o.u[2] = pkbf(b.x, b.y); o.u[3] = pkbf(b.z, b.w);
    *(ushortx8*)(dst + i) = o.s;
}

// ---------------------------------------------------------------------------
// MFMA GEMM core: 128x128 tile, BK=32, 4 waves each computing 64x64.
// ---------------------------------------------------------------------------
#define TM 128
#define TN 128
#define TK 32

// GEMM1: -> qkv bf16 (Q scaled 1/8*log2e) + V^T global [b,n,d,s]
__global__ __launch_bounds__(256) void gemm_mfma_qkv(
    const unsigned short* __restrict__ A, const unsigned short* __restrict__ Bw,
    const float* __restrict__ bias, unsigned short* __restrict__ qkvC,
    unsigned short* __restrict__ vT, int M, int Nd, int K)
{
    __shared__ unsigned short As[TM][TK];
    __shared__ unsigned short Bs[TN][TK];

    const int tid = threadIdx.x;
    const int w = tid >> 6, lane = tid & 63;
    const int l15 = lane & 15, quad = lane >> 4;
    const int wr = (w & 1) * 64;
    const int wc = (w >> 1) * 64;
    const int row0 = blockIdx.y * TM;
    const int col0 = blockIdx.x * TN;

    const int srow16 = lane >> 2;
    const int sgd    = lane & 3;
    const int sgsrc  = (sgd ^ swz(srow16)) * 8;

    floatx4 acc[4][4];
    #pragma unroll
    for (int i = 0; i < 4; i++)
        #pragma unroll
        for (int j = 0; j < 4; j++) acc[i][j] = (floatx4){0.f,0.f,0.f,0.f};

    const int aswz = swz(l15) * 8;

    for (int k0 = 0; k0 < K; k0 += TK) {
        __syncthreads();
        #pragma unroll
        for (int c = 0; c < 2; c++) {
            int seg = w * 2 + c;
            int r = seg * 16 + srow16;
            gload16(A  + (size_t)(row0 + r) * K + k0 + sgsrc, &As[seg * 16][0]);
            gload16(Bw + (size_t)(col0 + r) * K + k0 + sgsrc, &Bs[seg * 16][0]);
        }
        __syncthreads();

        short8 af[4], bf[4];
        #pragma unroll
        for (int i = 0; i < 4; i++)
            af[i] = *(const short8*)&As[wr + i * 16 + l15][(quad * 8) ^ aswz];
        #pragma unroll
        for (int j = 0; j < 4; j++)
            bf[j] = *(const short8*)&Bs[wc + j * 16 + l15][(quad * 8) ^ aswz];
        #pragma unroll
        for (int i = 0; i < 4; i++)
            #pragma unroll
            for (int j = 0; j < 4; j++)
                acc[i][j] = __builtin_amdgcn_mfma_f32_16x16x32_bf16(af[i], bf[j], acc[i][j], 0, 0, 0);
    }

    #pragma unroll
    for (int i = 0; i < 4; i++) {
        const int rb = row0 + wr + i * 16 + quad * 4;
        const int b  = rb >> 11;
        const int s  = rb & (Sq - 1);
        #pragma unroll
        for (int j = 0; j < 4; j++) {
            const int c = col0 + wc + j * 16 + l15;
            const float bia = bias[c];
            if (c < 2 * Hq) {
                // Q columns: fold 1/sqrt(64) and log2(e) for exp2-softmax
                const float scale = (c < Hq) ? (0.125f * LOG2E) : 1.0f;
                #pragma unroll
                for (int rr = 0; rr < 4; rr++)
                    qkvC[(size_t)(rb + rr) * Nd + c] = f2bf((acc[i][j][rr] + bia) * scale);
            } else {
                const int c2 = c - 2 * Hq;           // n*64+d
                ushortx4 o;
                #pragma unroll
                for (int rr = 0; rr < 4; rr++) o[rr] = f2bf(acc[i][j][rr] + bia);
                *(ushortx4*)&vT[((size_t)(b << 10) + c2) * Sq + s] = o;
            }
        }
    }
}

// GEMM2: x = A*Bw^T + bias + residual -> bf16 (LN reads bf16, stats in fp32)
__global__ __launch_bounds__(256) void gemm_mfma_out(
    const unsigned short* __restrict__ A, const unsigned short* __restrict__ Bw,
    const float* __restrict__ bias, const float* __restrict__ res,
    unsigned short* __restrict__ X, int M, int Nd, int K)
{
    __shared__ unsigned short As[TM][TK];
    __shared__ unsigned short Bs[TN][TK];

    const int tid = threadIdx.x;
    const int w = tid >> 6, lane = tid & 63;
    const int l15 = lane & 15, quad = lane >> 4;
    const int wr = (w & 1) * 64;
    const int wc = (w >> 1) * 64;
    const int row0 = blockIdx.y * TM;
    const int col0 = blockIdx.x * TN;

    const int srow16 = lane >> 2;
    const int sgd    = lane & 3;
    const int sgsrc  = (sgd ^ swz(srow16)) * 8;

    floatx4 acc[4][4];
    #pragma unroll
    for (int i = 0; i < 4; i++)
        #pragma unroll
        for (int j = 0; j < 4; j++) acc[i][j] = (floatx4){0.f,0.f,0.f,0.f};

    const int aswz = swz(l15) * 8;

    for (int k0 = 0; k0 < K; k0 += TK) {
        __syncthreads();
        #pragma unroll
        for (int c = 0; c < 2; c++) {
            int seg = w * 2 + c;
            int r = seg * 16 + srow16;
            gload16(A  + (size_t)(row0 + r) * K + k0 + sgsrc, &As[seg * 16][0]);
            gload16(Bw + (size_t)(col0 + r) * K + k0 + sgsrc, &Bs[seg * 16][0]);
        }
        __syncthreads();

        short8 af[4], bf[4];
        #pragma unroll
        for (int i = 0; i < 4; i++)
            af[i] = *(const short8*)&As[wr + i * 16 + l15][(quad * 8) ^ aswz];
        #pragma unroll
        for (int j = 0; j < 4; j++)
            bf[j] = *(const short8*)&Bs[wc + j * 16 + l15][(quad * 8) ^ aswz];
        #pragma unroll
        for (int i = 0; i < 4; i++)
            #pragma unroll
            for (int j = 0; j < 4; j++)
                acc[i][j] = __builtin_amdgcn_mfma_f32_16x16x32_bf16(af[i], bf[j], acc[i][j], 0, 0, 0);
    }

    #pragma unroll
    for (int i = 0; i < 4; i++) {
        const int rb = row0 + wr + i * 16 + quad * 4;
        #pragma unroll
        for (int j = 0; j < 4; j++) {
            const int c = col0 + wc + j * 16 + l15;
            const float bia = bias[c];
            #pragma unroll
            for (int rr = 0; rr < 4; rr++) {
                X[(size_t)(rb + rr) * Nd + c] =
                    f2bf(acc[i][j][rr] + bia + res[(size_t)(rb + rr) * Nd + c]);
            }
        }
    }
}

// ---------------------------------------------------------------------------
// Grid-split-K MFMA flash attention, 32 queries/wave (2 subtiles), z-split x2.
// Per tile: one af LDS read feeds 2 S^T MFMAs; one vf read feeds 2 PV MFMAs
// -> LDS bytes, staging, addressing per query HALVED vs R5/R9.
// Register discipline (the R8 spill fix): softmax runs SEQUENTIALLY per
// subtile so only one sacc bank is live past the S^T phase; peak ~110 VGPR
// under the (256,4) cap of 128. Streaming exp2 softmax (no running max) =>
// z-halves merge by plain addition in attn_merge.
// ---------------------------------------------------------------------------
#define KTILES 16   // 64-key tiles per z-half
#define PADW 72     // Ks row stride (bf16)

__global__ __launch_bounds__(256, 4) void attn_mfma(
    const unsigned short* __restrict__ qkv, const unsigned short* __restrict__ vT,
    const float* __restrict__ mask, unsigned short* __restrict__ Opart,
    float* __restrict__ Lpart)
{
    __shared__ unsigned short Ks[64][PADW];   // [key][d]
    __shared__ unsigned short Vt[64][64];     // [d][key], granule-XOR swizzled
    __shared__ float maskS[64];

    const int tid  = threadIdx.x;
    const int w    = tid >> 6;
    const int lane = tid & 63;
    const int l15  = lane & 15;
    const int quad = lane >> 4;

    const int qtile = blockIdx.x;     // 0..15 (128 queries each)
    const int bn    = blockIdx.y;
    const int z     = blockIdx.z;
    const int n     = bn & 15;
    const int b     = bn >> 4;

    const int qoff = n * HNq;
    const int koff = Hq + n * HNq;
    const int kbase = z * (KTILES * 64);

    // Q B-fragments for both subtiles (n=l15 -> query row, k=quad*8+j)
    short8 qfrag[2][2];
    #pragma unroll
    for (int sub = 0; sub < 2; sub++) {
        const int qrow = qtile * 128 + sub * 64 + w * 16 + l15;
        const unsigned short* qp = qkv + (size_t)(b * Sq + qrow) * H3q + qoff + quad * 8;
        qfrag[sub][0] = *(const short8*)(qp);
        qfrag[sub][1] = *(const short8*)(qp + 32);
    }

    floatx4 oacc0[4], oacc1[4];   // O^T per subtile
    #pragma unroll
    for (int dt = 0; dt < 4; dt++) {
        oacc0[dt] = (floatx4){0.f,0.f,0.f,0.f};
        oacc1[dt] = (floatx4){0.f,0.f,0.f,0.f};
    }
    float l_part0 = 0.f, l_part1 = 0.f;

    const int stg_k  = tid >> 2;          // 0..63
    const int stg_c0 = (tid & 3) * 16;
    const unsigned short* vbase = vT + (size_t)(b * Nq + n) * HNq * Sq;

    // V staging geometry (granule-XOR swizzle by d&7)
    const int vd0 = tid >> 3,        vg0 = tid & 7;
    const int vd1 = 32 + (tid >> 3), vg1 = tid & 7;

    // software pipeline: prefetch tile kt+1 during compute of kt
    ushortx8 kreg0, kreg1, vreg0, vreg1;
    float mreg;
    {
        const unsigned short* ks0 = qkv + (size_t)(b * Sq + kbase + stg_k) * H3q + koff + stg_c0;
        kreg0 = *(const ushortx8*)(ks0);
        kreg1 = *(const ushortx8*)(ks0 + 8);
        vreg0 = *(const ushortx8*)(vbase + (size_t)vd0 * Sq + kbase + vg0 * 8);
        vreg1 = *(const ushortx8*)(vbase + (size_t)vd1 * Sq + kbase + vg1 * 8);
        mreg  = (tid < 64) ? mask[(size_t)b * Sq + kbase + tid] * LOG2E : 0.f;
    }

    for (int kt = 0; kt < KTILES; kt++) {
        __syncthreads();
        // store staged tile to LDS
        *(ushortx8*)&Ks[stg_k][stg_c0]     = kreg0;
        *(ushortx8*)&Ks[stg_k][stg_c0 + 8] = kreg1;
        *(ushortx8*)&Vt[vd0][(vg0 ^ (vd0 & 7)) * 8] = vreg0;
        *(ushortx8*)&Vt[vd1][(vg1 ^ (vd1 & 7)) * 8] = vreg1;
        if (tid < 64) maskS[tid] = mreg;
        __syncthreads();

        // prefetch next tile
        if (kt + 1 < KTILES) {
            const int nk0 = kbase + (kt + 1) * 64;
            const unsigned short* ks0 = qkv + (size_t)(b * Sq + nk0 + stg_k) * H3q + koff + stg_c0;
            kreg0 = *(const ushortx8*)(ks0);
            kreg1 = *(const ushortx8*)(ks0 + 8);
            vreg0 = *(const ushortx8*)(vbase + (size_t)vd0 * Sq + nk0 + vg0 * 8);
            vreg1 = *(const ushortx8*)(vbase + (size_t)vd1 * Sq + nk0 + vg1 * 8);
            mreg  = (tid < 64) ? mask[(size_t)b * Sq + nk0 + tid] * LOG2E : 0.f;
        }

        // ---- S^T = K Q^T for both subtiles; each af read feeds 2 MFMAs
        floatx4 sacc0[4], sacc1[4];
        #pragma unroll
        for (int ct = 0; ct < 4; ct++) {
            sacc0[ct] = (floatx4){0.f,0.f,0.f,0.f};
            sacc1[ct] = (floatx4){0.f,0.f,0.f,0.f};
        }
        #pragma unroll
        for (int ks = 0; ks < 2; ks++) {
            #pragma unroll
            for (int ct = 0; ct < 4; ct++) {
                short8 af = *(const short8*)&Ks[ct * 16 + l15][ks * 32 + quad * 8];
                sacc0[ct] = __builtin_amdgcn_mfma_f32_16x16x32_bf16(af, qfrag[0][ks], sacc0[ct], 0, 0, 0);
                sacc1[ct] = __builtin_amdgcn_mfma_f32_16x16x32_bf16(af, qfrag[1][ks], sacc1[ct], 0, 0, 0);
            }
        }

        // ---- SEQUENTIAL streaming softmax (one sacc bank live at a time)
        short8 pf0[2], pf1[2];
        #pragma unroll
        for (int ks = 0; ks < 2; ks++) {
            union { unsigned int u[4]; short8 s; } pk;
            #pragma unroll
            for (int h = 0; h < 2; h++) {
                const int ct = ks * 2 + h;
                float4 mkv = *(const float4*)&maskS[ct * 16 + quad * 4];
                float p0 = exp2f(sacc0[ct][0] + mkv.x);
                float p1 = exp2f(sacc0[ct][1] + mkv.y);
                float p2 = exp2f(sacc0[ct][2] + mkv.z);
                float p3 = exp2f(sacc0[ct][3] + mkv.w);
                l_part0 += (p0 + p1) + (p2 + p3);
                pk.u[h * 2]     = pkbf(p0, p1);
                pk.u[h * 2 + 1] = pkbf(p2, p3);
            }
            pf0[ks] = pk.s;
        }
        #pragma unroll
        for (int ks = 0; ks < 2; ks++) {
            union { unsigned int u[4]; short8 s; } pk;
            #pragma unroll
            for (int h = 0; h < 2; h++) {
                const int ct = ks * 2 + h;
                float4 mkv = *(const float4*)&maskS[ct * 16 + quad * 4];
                float p0 = exp2f(sacc1[ct][0] + mkv.x);
                float p1 = exp2f(sacc1[ct][1] + mkv.y);
                float p2 = exp2f(sacc1[ct][2] + mkv.z);
                float p3 = exp2f(sacc1[ct][3] + mkv.w);
                l_part1 += (p0 + p1) + (p2 + p3);
                pk.u[h * 2]     = pkbf(p0, p1);
                pk.u[h * 2 + 1] = pkbf(p2, p3);
            }
            pf1[ks] = pk.s;
        }

        // ---- O^T += V^T P^T; each vf read feeds 2 MFMAs
        #pragma unroll
        for (int ks = 0; ks < 2; ks++) {
            const int c0 = (((4 * ks +     (quad >> 1)) ^ (l15 & 7)) * 8) + (quad & 1) * 4;
            const int c1 = (((4 * ks + 2 + (quad >> 1)) ^ (l15 & 7)) * 8) + (quad & 1) * 4;
            #pragma unroll
            for (int dt = 0; dt < 4; dt++) {
                const int d = dt * 16 + l15;
                short4s lo = *(const short4s*)&Vt[d][c0];
                short4s hi = *(const short4s*)&Vt[d][c1];
                short8 vf = __builtin_shufflevector(lo, hi, 0, 1, 2, 3, 4, 5, 6, 7);
                oacc0[dt] = __builtin_amdgcn_mfma_f32_16x16x32_bf16(vf, pf0[ks], oacc0[dt], 0, 0, 0);
                oacc1[dt] = __builtin_amdgcn_mfma_f32_16x16x32_bf16(vf, pf1[ks], oacc1[dt], 0, 0, 0);
            }
        }
    }

    // ---- epilogue: write un-normalized partial O (bf16) + per-query l
    unsigned short* Ow = Opart + (size_t)z * Mq * Hq;
    #pragma unroll
    for (int sub = 0; sub < 2; sub++) {
        float l_i = sub ? l_part1 : l_part0;
        l_i += __shfl_xor(l_i, 16, 64);
        l_i += __shfl_xor(l_i, 32, 64);
        const int qrow = qtile * 128 + sub * 64 + w * 16 + l15;
        if (quad == 0)
            Lpart[(size_t)z * Mq * Nq + (size_t)(b * Sq + qrow) * Nq + n] = l_i;
        #pragma unroll
        for (int dt = 0; dt < 4; dt++) {
            const floatx4 oa = sub ? oacc1[dt] : oacc0[dt];
            union { unsigned int u[2]; ushortx4 s; } o;
            o.u[0] = pkbf(oa[0], oa[1]);
            o.u[1] = pkbf(oa[2], oa[3]);
            const int col = n * HNq + dt * 16 + quad * 4;
            *(ushortx4*)&Ow[(size_t)(b * Sq + qrow) * Hq + col] = o.s;
        }
    }
}

// ---------------------------------------------------------------------------
// Merge the two split-K halves: ctx = (O0 + O1) / (l0 + l1), bf16 out.
// ---------------------------------------------------------------------------
__global__ __launch_bounds__(256) void attn_merge(
    const unsigned short* __restrict__ Opart, const float* __restrict__ Lpart,
    unsigned short* __restrict__ ctx)
{
    const size_t idx = ((size_t)blockIdx.x * 256 + threadIdx.x) * 4;
    const int row = (int)(idx >> 10);          // b*Sq + s
    const int n   = ((int)idx >> 6) & 15;
    const float l = Lpart[(size_t)row * Nq + n]
                  + Lpart[(size_t)Mq * Nq + (size_t)row * Nq + n];
    const float inv = 1.0f / l;
    ushortx4 a = *(const ushortx4*)(Opart + idx);
    ushortx4 c = *(const ushortx4*)(Opart + (size_t)Mq * Hq + idx);
    union { unsigned int u[2]; ushortx4 s; } o;
    o.u[0] = pkbf((bf2f(a[0]) + bf2f(c[0])) * inv, (bf2f(a[1]) + bf2f(c[1])) * inv);
    o.u[1] = pkbf((bf2f(a[2]) + bf2f(c[2])) * inv, (bf2f(a[3]) + bf2f(c[3])) * inv);
    *(ushortx4*)(ctx + idx) = o.s;
}

// ---------------------------------------------------------------------------
// Row LayerNorm over H=1024, bf16 input, fp32 stats, fp32 output.
// ---------------------------------------------------------------------------
__global__ __launch_bounds__(256) void ln_kernel(
    const unsigned short* __restrict__ X, const float* __restrict__ gamma,
    const float* __restrict__ beta, float* __restrict__ out)
{
    const int row = blockIdx.x;
    const int c0  = threadIdx.x * 4;
    ushortx4 xv = *(const ushortx4*)(X + (size_t)row * Hq + c0);
    float vals[4];
    float lsum = 0.0f;
    #pragma unroll
    for (int i = 0; i < 4; i++) { vals[i] = bf2f(xv[i]); lsum += vals[i]; }

    __shared__ float red[8];
    const int wid = threadIdx.x >> 6, lane = threadIdx.x & 63;

    float s = lsum;
    #pragma unroll
    for (int off = 32; off >= 1; off >>= 1) s += __shfl_xor(s, off, 64);
    if (lane == 0) red[wid] = s;
    __syncthreads();
    const float mean = (red[0] + red[1] + red[2] + red[3]) * (1.0f / Hq);

    float v = 0.0f;
    #pragma unroll
    for (int i = 0; i < 4; i++) { float d = vals[i] - mean; v += d * d; }
    #pragma unroll
    for (int off = 32; off >= 1; off >>= 1) v += __shfl_xor(v, off, 64);
    if (lane == 0) red[4 + wid] = v;
    __syncthreads();
    const float var  = (red[4] + red[5] + red[6] + red[7]) * (1.0f / Hq);
    const float rstd = rsqrtf(var + 1e-12f);

    float4 gm = *(const float4*)(gamma + c0);
    float4 bt = *(const float4*)(beta + c0);
    float4 o;
    o.x = (vals[0] - mean) * rstd * gm.x + bt.x;
    o.y = (vals[1] - mean) * rstd * gm.y + bt.y;
    o.z = (vals[2] - mean) * rstd * gm.z + bt.z;
    o.w = (vals[3] - mean) * rstd * gm.w + bt.w;
    *(float4*)(out + (size_t)row * Hq + c0) = o;
}

// ---------------------------------------------------------------------------
extern "C" void kernel_launch(void* const* d_in, const int* in_sizes, int n_in,
                              void* d_out, int out_size, void* d_ws, size_t ws_size,
                              hipStream_t stream)
{
    const float* hidden = (const float*)d_in[0];
    const float* mask   = (const float*)d_in[1];
    const float* W_qkv  = (const float*)d_in[2];
    const float* b_qkv  = (const float*)d_in[3];
    const float* W_out  = (const float*)d_in[4];
    const float* b_out  = (const float*)d_in[5];
    const float* gamma  = (const float*)d_in[6];
    const float* beta   = (const float*)d_in[7];
    float* out = (float*)d_out;

    const size_t nHid  = (size_t)Mq * Hq;        // 4 M
    const size_t nWq   = (size_t)H3q * Hq;       // 3 M
    const size_t nWo   = (size_t)Hq * Hq;        // 1 M
    const size_t nQKV  = (size_t)Mq * H3q;       // 12 M
    const size_t nVT   = (size_t)Bq * Hq * Sq;   // 4 M
    const size_t nCtx  = (size_t)Mq * Hq;        // 4 M

    unsigned short* hidden_bf = (unsigned short*)d_ws;
    unsigned short* Wqkv_bf   = hidden_bf + nHid;
    unsigned short* Wout_bf   = Wqkv_bf + nWq;
    unsigned short* qkv_bf    = Wout_bf + nWo;
    unsigned short* vT        = qkv_bf + nQKV;
    unsigned short* ctx_bf    = vT + nVT;
    unsigned short* x_bf      = ctx_bf + nCtx;
    unsigned short* opart     = x_bf + nHid;           // 2 * 4M bf16 = 16 MB
    float*          lpart     = (float*)(opart + 2 * nHid);  // 2*64K floats

    dim3 blk(256);

    // 0) fused fp32 -> bf16 cast (hidden | W_qkv | W_out contiguous dst)
    cvt_all<<<dim3((int)(N_ALL / 2048)), blk, 0, stream>>>(
        hidden, W_qkv, W_out, hidden_bf);

    // 1) QKV projection (MFMA) -> qkv bf16 (Q/K) + V^T
    gemm_mfma_qkv<<<dim3(H3q / TN, Mq / TM), blk, 0, stream>>>(
        hidden_bf, Wqkv_bf, b_qkv, qkv_bf, vT, Mq, H3q, Hq);

    // 2) Grid-split-K MFMA flash attention (32 q/wave) -> partial O/l
    attn_mfma<<<dim3(Sq / 128, Bq * Nq, 2), blk, 0, stream>>>(
        qkv_bf, vT, mask, opart, lpart);

    // 2b) merge halves -> ctx bf16
    attn_merge<<<dim3((int)(nCtx / 1024)), blk, 0, stream>>>(
        opart, lpart, ctx_bf);

    // 3) Output projection (MFMA) + bias + residual -> x bf16
    gemm_mfma_out<<<dim3(Hq / TN, Mq / TM), blk, 0, stream>>>(
        ctx_bf, Wout_bf, b_out, hidden, x_bf, Mq, Hq, Hq);

    // 4) LayerNorm: bf16 x -> fp32 out
    ln_kernel<<<dim3(Mq), blk, 0, stream>>>(x_bf, gamma, beta, out);
}

// Round 11
// 246.343 us; speedup vs baseline: 1.2926x; 1.2926x over previous
//
#include <hip/hip_runtime.h>
#include <hip/hip_bf16.h>
#include <math.h>

// Problem constants
#define Bq  2
#define Sq  2048
#define Hq  1024
#define Nq  16
#define HNq 64
#define Mq  (Bq*Sq)        // 4096 rows
#define H3q (3*Hq)         // 3072

#define LOG2E 1.44269504088896340736f

typedef __attribute__((ext_vector_type(8))) short           short8;
typedef __attribute__((ext_vector_type(4))) short           short4s;
typedef __attribute__((ext_vector_type(8))) unsigned short  ushortx8;
typedef __attribute__((ext_vector_type(4))) unsigned short  ushortx4;
typedef __attribute__((ext_vector_type(4))) float           floatx4;

__device__ __forceinline__ unsigned short f2bf(float f) {
    union { float f; unsigned int u; } x; x.f = f;
    unsigned int r = (x.u + 0x7fffu + ((x.u >> 16) & 1u)) >> 16;
    return (unsigned short)r;
}

// packed fp32x2 -> bf16x2 (v_cvt_pk_bf16_f32 on gfx950); a in low 16 bits
__device__ __forceinline__ unsigned int pkbf(float a, float b) {
    float2 t; t.x = a; t.y = b;
    __hip_bfloat162 h = __float22bfloat162_rn(t);
    union { __hip_bfloat162 h; unsigned int u; } c; c.h = h;
    return c.u;
}

__device__ __forceinline__ float bf2f(unsigned short v) {
    union { unsigned int u; float f; } x; x.u = (unsigned int)v << 16;
    return x.f;
}

// async global->LDS, 16B per lane; LDS dest = wave-uniform base + lane*16
__device__ __forceinline__ void gload16(const unsigned short* g, unsigned short* l) {
    __builtin_amdgcn_global_load_lds(
        (__attribute__((address_space(1))) void*)(unsigned long long)(g),
        (__attribute__((address_space(3))) void*)(unsigned int)(unsigned long long)(l),
        16, 0, 0);
}

// LDS bank swizzle: granule' = granule ^ swz(row mod 16); 2-way max conflict
__device__ __forceinline__ int swz(int r) { return (r ^ (r >> 2)) & 3; }

// ---------------------------------------------------------------------------
// Fused fp32 -> bf16 cast for hidden | W_qkv | W_out (contiguous bf16 dst)
// ---------------------------------------------------------------------------
#define N_HID ((size_t)Mq * Hq)          // 4194304
#define N_HW  (N_HID + (size_t)H3q * Hq) // 7340032
#define N_ALL (N_HW + (size_t)Hq * Hq)   // 8388608

__global__ __launch_bounds__(256) void cvt_all(
    const float* __restrict__ hidden, const float* __restrict__ wqkv,
    const float* __restrict__ wout, unsigned short* __restrict__ dst)
{
    size_t i = ((size_t)blockIdx.x * 256 + threadIdx.x) * 8;
    const float* src;
    if (i < N_HID)      src = hidden + i;
    else if (i < N_HW)  src = wqkv + (i - N_HID);
    else                src = wout + (i - N_HW);
    float4 a = *(const float4*)(src);
    float4 b = *(const float4*)(src + 4);
    union { unsigned int u[4]; ushortx8 s; } o;
    o.u[0] = pkbf(a.x, a.y); o.u[1] = pkbf(a.z, a.w);
    o.u[2] = pkbf(b.x, b.y); o.u[3] = pkbf(b.z, b.w);
    *(ushortx8*)(dst + i) = o.s;
}

// ---------------------------------------------------------------------------
// MFMA GEMM core: 128x128 tile, BK=32, 4 waves each computing 64x64.
// ---------------------------------------------------------------------------
#define TM 128
#define TN 128
#define TK 32

// GEMM1: -> qkv bf16 (Q scaled 1/8*log2e) + V^T global [b,n,d,s]
__global__ __launch_bounds__(256) void gemm_mfma_qkv(
    const unsigned short* __restrict__ A, const unsigned short* __restrict__ Bw,
    const float* __restrict__ bias, unsigned short* __restrict__ qkvC,
    unsigned short* __restrict__ vT, int M, int Nd, int K)
{
    __shared__ unsigned short As[TM][TK];
    __shared__ unsigned short Bs[TN][TK];

    const int tid = threadIdx.x;
    const int w = tid >> 6, lane = tid & 63;
    const int l15 = lane & 15, quad = lane >> 4;
    const int wr = (w & 1) * 64;
    const int wc = (w >> 1) * 64;
    const int row0 = blockIdx.y * TM;
    const int col0 = blockIdx.x * TN;

    const int srow16 = lane >> 2;
    const int sgd    = lane & 3;
    const int sgsrc  = (sgd ^ swz(srow16)) * 8;

    floatx4 acc[4][4];
    #pragma unroll
    for (int i = 0; i < 4; i++)
        #pragma unroll
        for (int j = 0; j < 4; j++) acc[i][j] = (floatx4){0.f,0.f,0.f,0.f};

    const int aswz = swz(l15) * 8;

    for (int k0 = 0; k0 < K; k0 += TK) {
        __syncthreads();
        #pragma unroll
        for (int c = 0; c < 2; c++) {
            int seg = w * 2 + c;
            int r = seg * 16 + srow16;
            gload16(A  + (size_t)(row0 + r) * K + k0 + sgsrc, &As[seg * 16][0]);
            gload16(Bw + (size_t)(col0 + r) * K + k0 + sgsrc, &Bs[seg * 16][0]);
        }
        __syncthreads();

        short8 af[4], bf[4];
        #pragma unroll
        for (int i = 0; i < 4; i++)
            af[i] = *(const short8*)&As[wr + i * 16 + l15][(quad * 8) ^ aswz];
        #pragma unroll
        for (int j = 0; j < 4; j++)
            bf[j] = *(const short8*)&Bs[wc + j * 16 + l15][(quad * 8) ^ aswz];
        #pragma unroll
        for (int i = 0; i < 4; i++)
            #pragma unroll
            for (int j = 0; j < 4; j++)
                acc[i][j] = __builtin_amdgcn_mfma_f32_16x16x32_bf16(af[i], bf[j], acc[i][j], 0, 0, 0);
    }

    #pragma unroll
    for (int i = 0; i < 4; i++) {
        const int rb = row0 + wr + i * 16 + quad * 4;
        const int b  = rb >> 11;
        const int s  = rb & (Sq - 1);
        #pragma unroll
        for (int j = 0; j < 4; j++) {
            const int c = col0 + wc + j * 16 + l15;
            const float bia = bias[c];
            if (c < 2 * Hq) {
                // Q columns: fold 1/sqrt(64) and log2(e) for exp2-softmax
                const float scale = (c < Hq) ? (0.125f * LOG2E) : 1.0f;
                #pragma unroll
                for (int rr = 0; rr < 4; rr++)
                    qkvC[(size_t)(rb + rr) * Nd + c] = f2bf((acc[i][j][rr] + bia) * scale);
            } else {
                const int c2 = c - 2 * Hq;           // n*64+d
                ushortx4 o;
                #pragma unroll
                for (int rr = 0; rr < 4; rr++) o[rr] = f2bf(acc[i][j][rr] + bia);
                *(ushortx4*)&vT[((size_t)(b << 10) + c2) * Sq + s] = o;
            }
        }
    }
}

// GEMM2: x = A*Bw^T + bias + residual -> bf16 (LN reads bf16, stats in fp32)
__global__ __launch_bounds__(256) void gemm_mfma_out(
    const unsigned short* __restrict__ A, const unsigned short* __restrict__ Bw,
    const float* __restrict__ bias, const float* __restrict__ res,
    unsigned short* __restrict__ X, int M, int Nd, int K)
{
    __shared__ unsigned short As[TM][TK];
    __shared__ unsigned short Bs[TN][TK];

    const int tid = threadIdx.x;
    const int w = tid >> 6, lane = tid & 63;
    const int l15 = lane & 15, quad = lane >> 4;
    const int wr = (w & 1) * 64;
    const int wc = (w >> 1) * 64;
    const int row0 = blockIdx.y * TM;
    const int col0 = blockIdx.x * TN;

    const int srow16 = lane >> 2;
    const int sgd    = lane & 3;
    const int sgsrc  = (sgd ^ swz(srow16)) * 8;

    floatx4 acc[4][4];
    #pragma unroll
    for (int i = 0; i < 4; i++)
        #pragma unroll
        for (int j = 0; j < 4; j++) acc[i][j] = (floatx4){0.f,0.f,0.f,0.f};

    const int aswz = swz(l15) * 8;

    for (int k0 = 0; k0 < K; k0 += TK) {
        __syncthreads();
        #pragma unroll
        for (int c = 0; c < 2; c++) {
            int seg = w * 2 + c;
            int r = seg * 16 + srow16;
            gload16(A  + (size_t)(row0 + r) * K + k0 + sgsrc, &As[seg * 16][0]);
            gload16(Bw + (size_t)(col0 + r) * K + k0 + sgsrc, &Bs[seg * 16][0]);
        }
        __syncthreads();

        short8 af[4], bf[4];
        #pragma unroll
        for (int i = 0; i < 4; i++)
            af[i] = *(const short8*)&As[wr + i * 16 + l15][(quad * 8) ^ aswz];
        #pragma unroll
        for (int j = 0; j < 4; j++)
            bf[j] = *(const short8*)&Bs[wc + j * 16 + l15][(quad * 8) ^ aswz];
        #pragma unroll
        for (int i = 0; i < 4; i++)
            #pragma unroll
            for (int j = 0; j < 4; j++)
                acc[i][j] = __builtin_amdgcn_mfma_f32_16x16x32_bf16(af[i], bf[j], acc[i][j], 0, 0, 0);
    }

    #pragma unroll
    for (int i = 0; i < 4; i++) {
        const int rb = row0 + wr + i * 16 + quad * 4;
        #pragma unroll
        for (int j = 0; j < 4; j++) {
            const int c = col0 + wc + j * 16 + l15;
            const float bia = bias[c];
            #pragma unroll
            for (int rr = 0; rr < 4; rr++) {
                X[(size_t)(rb + rr) * Nd + c] =
                    f2bf(acc[i][j][rr] + bia + res[(size_t)(rb + rr) * Nd + c]);
            }
        }
    }
}

// ---------------------------------------------------------------------------
// Grid-split-K MFMA flash attention, 32 queries/wave (2 q-subtiles), z-split.
// Register-budget fix vs R10's spill: K staged via global_load_lds (no kreg
// registers, no ds_write for K), Ks[64][64] with XOR-granule swizzle realized
// in the SOURCE address (lane loads src granule g^(row&7)); V register-staged
// (swizzle incompatible with DMA); NO min-waves clause so the allocator never
// spills. Each af/vf LDS read feeds 2 MFMAs -> LDS+staging per query halved.
// Streaming exp2 softmax (no running max); z-halves merge by plain addition.
// ---------------------------------------------------------------------------
#define KTILES 16   // 64-key tiles per z-half

__global__ __launch_bounds__(256) void attn_mfma(
    const unsigned short* __restrict__ qkv, const unsigned short* __restrict__ vT,
    const float* __restrict__ mask, unsigned short* __restrict__ Opart,
    float* __restrict__ Lpart)
{
    __shared__ unsigned short Ks[64][64];   // [key][d], src-granule swizzled
    __shared__ unsigned short Vt[64][64];   // [d][key], granule-XOR swizzled
    __shared__ float maskS[64];

    const int tid  = threadIdx.x;
    const int w    = tid >> 6;
    const int lane = tid & 63;
    const int l15  = lane & 15;
    const int quad = lane >> 4;

    const int qtile = blockIdx.x;     // 0..15 (128 queries each)
    const int bn    = blockIdx.y;
    const int z     = blockIdx.z;
    const int n     = bn & 15;
    const int b     = bn >> 4;

    const int qoff = n * HNq;
    const int koff = Hq + n * HNq;
    const int kbase = z * (KTILES * 64);

    // Q B-fragments for both subtiles (n=l15 -> query row, k=quad*8+j)
    short8 qfrag0[2], qfrag1[2];
    {
        const int qrow0 = qtile * 128 + w * 16 + l15;
        const unsigned short* qp = qkv + (size_t)(b * Sq + qrow0) * H3q + qoff + quad * 8;
        qfrag0[0] = *(const short8*)(qp);
        qfrag0[1] = *(const short8*)(qp + 32);
        qp += (size_t)64 * H3q;
        qfrag1[0] = *(const short8*)(qp);
        qfrag1[1] = *(const short8*)(qp + 32);
    }

    floatx4 oacc0[4], oacc1[4];   // O^T per subtile: d = dt*16+quad*4+r, q=l15
    #pragma unroll
    for (int dt = 0; dt < 4; dt++) {
        oacc0[dt] = (floatx4){0.f,0.f,0.f,0.f};
        oacc1[dt] = (floatx4){0.f,0.f,0.f,0.f};
    }
    float l_part0 = 0.f, l_part1 = 0.f;

    // K DMA geometry: wave w stages rows w*16..w*16+15 via 2 global_load_lds.
    // lane -> row w*16 + c*8 + (lane>>3), src granule (lane&7)^(row&7).
    const int krow8 = lane >> 3;               // 0..7
    const int kgr   = (lane & 7) ^ (krow8 & 7);
    const unsigned short* kp0 = qkv + (size_t)(b * Sq + kbase + w * 16 + krow8) * H3q + koff + kgr * 8;
    const unsigned short* kp1 = kp0 + (size_t)8 * H3q;
    unsigned short* kd0 = &Ks[w * 16][0];
    unsigned short* kd1 = &Ks[w * 16 + 8][0];
    const size_t kstep = (size_t)64 * H3q;

    // V staging geometry (granule-XOR swizzle by d&7)
    const int vd0 = tid >> 3,        vg0 = tid & 7;
    const int vd1 = 32 + (tid >> 3), vg1 = tid & 7;
    const unsigned short* vbase = vT + (size_t)(b * Nq + n) * HNq * Sq;

    // preload V/mask registers for tile 0
    ushortx8 vreg0, vreg1;
    float mreg;
    {
        vreg0 = *(const ushortx8*)(vbase + (size_t)vd0 * Sq + kbase + vg0 * 8);
        vreg1 = *(const ushortx8*)(vbase + (size_t)vd1 * Sq + kbase + vg1 * 8);
        mreg  = (tid < 64) ? mask[(size_t)b * Sq + kbase + tid] * LOG2E : 0.f;
    }

    for (int kt = 0; kt < KTILES; kt++) {
        __syncthreads();   // previous tile fully consumed
        // async K DMA for this tile + store V/mask regs
        gload16(kp0, kd0);
        gload16(kp1, kd1);
        kp0 += kstep; kp1 += kstep;
        *(ushortx8*)&Vt[vd0][(vg0 ^ (vd0 & 7)) * 8] = vreg0;
        *(ushortx8*)&Vt[vd1][(vg1 ^ (vd1 & 7)) * 8] = vreg1;
        if (tid < 64) maskS[tid] = mreg;
        __syncthreads();   // implicit vmcnt(0): K DMA landed, V stores visible

        // prefetch V/mask for next tile
        if (kt + 1 < KTILES) {
            const int nk0 = kbase + (kt + 1) * 64;
            vreg0 = *(const ushortx8*)(vbase + (size_t)vd0 * Sq + nk0 + vg0 * 8);
            vreg1 = *(const ushortx8*)(vbase + (size_t)vd1 * Sq + nk0 + vg1 * 8);
            mreg  = (tid < 64) ? mask[(size_t)b * Sq + nk0 + tid] * LOG2E : 0.f;
        }

        // ---- S^T = K Q^T for both subtiles; each af read feeds 2 MFMAs
        floatx4 sacc0[4], sacc1[4];
        #pragma unroll
        for (int ct = 0; ct < 4; ct++) {
            sacc0[ct] = (floatx4){0.f,0.f,0.f,0.f};
            sacc1[ct] = (floatx4){0.f,0.f,0.f,0.f};
        }
        #pragma unroll
        for (int ks = 0; ks < 2; ks++) {
            #pragma unroll
            for (int ct = 0; ct < 4; ct++) {
                short8 af = *(const short8*)&Ks[ct * 16 + l15][((4 * ks + quad) ^ (l15 & 7)) * 8];
                sacc0[ct] = __builtin_amdgcn_mfma_f32_16x16x32_bf16(af, qfrag0[ks], sacc0[ct], 0, 0, 0);
                sacc1[ct] = __builtin_amdgcn_mfma_f32_16x16x32_bf16(af, qfrag1[ks], sacc1[ct], 0, 0, 0);
            }
        }

        // ---- sequential streaming softmax (one sacc bank live at a time)
        short8 pf0[2], pf1[2];   // pf[ks][(ct&1)*4+r] = P(key=16ct+4quad+r)
        #pragma unroll
        for (int ks = 0; ks < 2; ks++) {
            union { unsigned int u[4]; short8 s; } pk;
            #pragma unroll
            for (int h = 0; h < 2; h++) {
                const int ct = ks * 2 + h;
                float4 mkv = *(const float4*)&maskS[ct * 16 + quad * 4];
                float p0 = exp2f(sacc0[ct][0] + mkv.x);
                float p1 = exp2f(sacc0[ct][1] + mkv.y);
                float p2 = exp2f(sacc0[ct][2] + mkv.z);
                float p3 = exp2f(sacc0[ct][3] + mkv.w);
                l_part0 += (p0 + p1) + (p2 + p3);
                pk.u[h * 2]     = pkbf(p0, p1);
                pk.u[h * 2 + 1] = pkbf(p2, p3);
            }
            pf0[ks] = pk.s;
        }
        #pragma unroll
        for (int ks = 0; ks < 2; ks++) {
            union { unsigned int u[4]; short8 s; } pk;
            #pragma unroll
            for (int h = 0; h < 2; h++) {
                const int ct = ks * 2 + h;
                float4 mkv = *(const float4*)&maskS[ct * 16 + quad * 4];
                float p0 = exp2f(sacc1[ct][0] + mkv.x);
                float p1 = exp2f(sacc1[ct][1] + mkv.y);
                float p2 = exp2f(sacc1[ct][2] + mkv.z);
                float p3 = exp2f(sacc1[ct][3] + mkv.w);
                l_part1 += (p0 + p1) + (p2 + p3);
                pk.u[h * 2]     = pkbf(p0, p1);
                pk.u[h * 2 + 1] = pkbf(p2, p3);
            }
            pf1[ks] = pk.s;
        }

        // ---- O^T += V^T P^T; each vf read feeds 2 MFMAs
        #pragma unroll
        for (int ks = 0; ks < 2; ks++) {
            const int c0 = (((4 * ks +     (quad >> 1)) ^ (l15 & 7)) * 8) + (quad & 1) * 4;
            const int c1 = (((4 * ks + 2 + (quad >> 1)) ^ (l15 & 7)) * 8) + (quad & 1) * 4;
            #pragma unroll
            for (int dt = 0; dt < 4; dt++) {
                const int d = dt * 16 + l15;
                short4s lo = *(const short4s*)&Vt[d][c0];
                short4s hi = *(const short4s*)&Vt[d][c1];
                short8 vf = __builtin_shufflevector(lo, hi, 0, 1, 2, 3, 4, 5, 6, 7);
                oacc0[dt] = __builtin_amdgcn_mfma_f32_16x16x32_bf16(vf, pf0[ks], oacc0[dt], 0, 0, 0);
                oacc1[dt] = __builtin_amdgcn_mfma_f32_16x16x32_bf16(vf, pf1[ks], oacc1[dt], 0, 0, 0);
            }
        }
    }

    // ---- epilogue: write un-normalized partial O (bf16) + per-query l
    unsigned short* Ow = Opart + (size_t)z * Mq * Hq;
    #pragma unroll
    for (int sub = 0; sub < 2; sub++) {
        float l_i = sub ? l_part1 : l_part0;
        l_i += __shfl_xor(l_i, 16, 64);
        l_i += __shfl_xor(l_i, 32, 64);
        const int qrow = qtile * 128 + sub * 64 + w * 16 + l15;
        if (quad == 0)
            Lpart[(size_t)z * Mq * Nq + (size_t)(b * Sq + qrow) * Nq + n] = l_i;
        #pragma unroll
        for (int dt = 0; dt < 4; dt++) {
            const floatx4 oa = sub ? oacc1[dt] : oacc0[dt];
            union { unsigned int u[2]; ushortx4 s; } o;
            o.u[0] = pkbf(oa[0], oa[1]);
            o.u[1] = pkbf(oa[2], oa[3]);
            const int col = n * HNq + dt * 16 + quad * 4;
            *(ushortx4*)&Ow[(size_t)(b * Sq + qrow) * Hq + col] = o.s;
        }
    }
}

// ---------------------------------------------------------------------------
// Merge the two split-K halves: ctx = (O0 + O1) / (l0 + l1), bf16 out.
// ---------------------------------------------------------------------------
__global__ __launch_bounds__(256) void attn_merge(
    const unsigned short* __restrict__ Opart, const float* __restrict__ Lpart,
    unsigned short* __restrict__ ctx)
{
    const size_t idx = ((size_t)blockIdx.x * 256 + threadIdx.x) * 4;
    const int row = (int)(idx >> 10);          // b*Sq + s
    const int n   = ((int)idx >> 6) & 15;
    const float l = Lpart[(size_t)row * Nq + n]
                  + Lpart[(size_t)Mq * Nq + (size_t)row * Nq + n];
    const float inv = 1.0f / l;
    ushortx4 a = *(const ushortx4*)(Opart + idx);
    ushortx4 c = *(const ushortx4*)(Opart + (size_t)Mq * Hq + idx);
    union { unsigned int u[2]; ushortx4 s; } o;
    o.u[0] = pkbf((bf2f(a[0]) + bf2f(c[0])) * inv, (bf2f(a[1]) + bf2f(c[1])) * inv);
    o.u[1] = pkbf((bf2f(a[2]) + bf2f(c[2])) * inv, (bf2f(a[3]) + bf2f(c[3])) * inv);
    *(ushortx4*)(ctx + idx) = o.s;
}

// ---------------------------------------------------------------------------
// Row LayerNorm over H=1024, bf16 input, fp32 stats, fp32 output.
// ---------------------------------------------------------------------------
__global__ __launch_bounds__(256) void ln_kernel(
    const unsigned short* __restrict__ X, const float* __restrict__ gamma,
    const float* __restrict__ beta, float* __restrict__ out)
{
    const int row = blockIdx.x;
    const int c0  = threadIdx.x * 4;
    ushortx4 xv = *(const ushortx4*)(X + (size_t)row * Hq + c0);
    float vals[4];
    float lsum = 0.0f;
    #pragma unroll
    for (int i = 0; i < 4; i++) { vals[i] = bf2f(xv[i]); lsum += vals[i]; }

    __shared__ float red[8];
    const int wid = threadIdx.x >> 6, lane = threadIdx.x & 63;

    float s = lsum;
    #pragma unroll
    for (int off = 32; off >= 1; off >>= 1) s += __shfl_xor(s, off, 64);
    if (lane == 0) red[wid] = s;
    __syncthreads();
    const float mean = (red[0] + red[1] + red[2] + red[3]) * (1.0f / Hq);

    float v = 0.0f;
    #pragma unroll
    for (int i = 0; i < 4; i++) { float d = vals[i] - mean; v += d * d; }
    #pragma unroll
    for (int off = 32; off >= 1; off >>= 1) v += __shfl_xor(v, off, 64);
    if (lane == 0) red[4 + wid] = v;
    __syncthreads();
    const float var  = (red[4] + red[5] + red[6] + red[7]) * (1.0f / Hq);
    const float rstd = rsqrtf(var + 1e-12f);

    float4 gm = *(const float4*)(gamma + c0);
    float4 bt = *(const float4*)(beta + c0);
    float4 o;
    o.x = (vals[0] - mean) * rstd * gm.x + bt.x;
    o.y = (vals[1] - mean) * rstd * gm.y + bt.y;
    o.z = (vals[2] - mean) * rstd * gm.z + bt.z;
    o.w = (vals[3] - mean) * rstd * gm.w + bt.w;
    *(float4*)(out + (size_t)row * Hq + c0) = o;
}

// ---------------------------------------------------------------------------
extern "C" void kernel_launch(void* const* d_in, const int* in_sizes, int n_in,
                              void* d_out, int out_size, void* d_ws, size_t ws_size,
                              hipStream_t stream)
{
    const float* hidden = (const float*)d_in[0];
    const float* mask   = (const float*)d_in[1];
    const float* W_qkv  = (const float*)d_in[2];
    const float* b_qkv  = (const float*)d_in[3];
    const float* W_out  = (const float*)d_in[4];
    const float* b_out  = (const float*)d_in[5];
    const float* gamma  = (const float*)d_in[6];
    const float* beta   = (const float*)d_in[7];
    float* out = (float*)d_out;

    const size_t nHid  = (size_t)Mq * Hq;        // 4 M
    const size_t nWq   = (size_t)H3q * Hq;       // 3 M
    const size_t nWo   = (size_t)Hq * Hq;        // 1 M
    const size_t nQKV  = (size_t)Mq * H3q;       // 12 M
    const size_t nVT   = (size_t)Bq * Hq * Sq;   // 4 M
    const size_t nCtx  = (size_t)Mq * Hq;        // 4 M

    unsigned short* hidden_bf = (unsigned short*)d_ws;
    unsigned short* Wqkv_bf   = hidden_bf + nHid;
    unsigned short* Wout_bf   = Wqkv_bf + nWq;
    unsigned short* qkv_bf    = Wout_bf + nWo;
    unsigned short* vT        = qkv_bf + nQKV;
    unsigned short* ctx_bf    = vT + nVT;
    unsigned short* x_bf      = ctx_bf + nCtx;
    unsigned short* opart     = x_bf + nHid;           // 2 * 4M bf16 = 16 MB
    float*          lpart     = (float*)(opart + 2 * nHid);  // 2*64K floats

    dim3 blk(256);

    // 0) fused fp32 -> bf16 cast (hidden | W_qkv | W_out contiguous dst)
    cvt_all<<<dim3((int)(N_ALL / 2048)), blk, 0, stream>>>(
        hidden, W_qkv, W_out, hidden_bf);

    // 1) QKV projection (MFMA) -> qkv bf16 (Q/K) + V^T
    gemm_mfma_qkv<<<dim3(H3q / TN, Mq / TM), blk, 0, stream>>>(
        hidden_bf, Wqkv_bf, b_qkv, qkv_bf, vT, Mq, H3q, Hq);

    // 2) Grid-split-K MFMA flash attention (32 q/wave) -> partial O/l
    attn_mfma<<<dim3(Sq / 128, Bq * Nq, 2), blk, 0, stream>>>(
        qkv_bf, vT, mask, opart, lpart);

    // 2b) merge halves -> ctx bf16
    attn_merge<<<dim3((int)(nCtx / 1024)), blk, 0, stream>>>(
        opart, lpart, ctx_bf);

    // 3) Output projection (MFMA) + bias + residual -> x bf16
    gemm_mfma_out<<<dim3(Hq / TN, Mq / TM), blk, 0, stream>>>(
        ctx_bf, Wout_bf, b_out, hidden, x_bf, Mq, Hq, Hq);

    // 4) LayerNorm: bf16 x -> fp32 out
    ln_kernel<<<dim3(Mq), blk, 0, stream>>>(x_bf, gamma, beta, out);
}

// Round 12
// 235.462 us; speedup vs baseline: 1.3523x; 1.0462x over previous
//
#include <hip/hip_runtime.h>
#include <hip/hip_bf16.h>
#include <math.h>

// Problem constants
#define Bq  2
#define Sq  2048
#define Hq  1024
#define Nq  16
#define HNq 64
#define Mq  (Bq*Sq)        // 4096 rows
#define H3q (3*Hq)         // 3072

#define LOG2E 1.44269504088896340736f

typedef __attribute__((ext_vector_type(8))) short           short8;
typedef __attribute__((ext_vector_type(4))) short           short4s;
typedef __attribute__((ext_vector_type(8))) unsigned short  ushortx8;
typedef __attribute__((ext_vector_type(4))) unsigned short  ushortx4;
typedef __attribute__((ext_vector_type(4))) float           floatx4;

__device__ __forceinline__ unsigned short f2bf(float f) {
    union { float f; unsigned int u; } x; x.f = f;
    unsigned int r = (x.u + 0x7fffu + ((x.u >> 16) & 1u)) >> 16;
    return (unsigned short)r;
}

// packed fp32x2 -> bf16x2 (v_cvt_pk_bf16_f32 on gfx950); a in low 16 bits
__device__ __forceinline__ unsigned int pkbf(float a, float b) {
    float2 t; t.x = a; t.y = b;
    __hip_bfloat162 h = __float22bfloat162_rn(t);
    union { __hip_bfloat162 h; unsigned int u; } c; c.h = h;
    return c.u;
}

__device__ __forceinline__ float bf2f(unsigned short v) {
    union { unsigned int u; float f; } x; x.u = (unsigned int)v << 16;
    return x.f;
}

// async global->LDS, 16B per lane; LDS dest = wave-uniform base + lane*16
__device__ __forceinline__ void gload16(const unsigned short* g, unsigned short* l) {
    __builtin_amdgcn_global_load_lds(
        (__attribute__((address_space(1))) void*)(unsigned long long)(g),
        (__attribute__((address_space(3))) void*)(unsigned int)(unsigned long long)(l),
        16, 0, 0);
}

// LDS bank swizzle: granule' = granule ^ swz(row mod 16); 2-way max conflict
__device__ __forceinline__ int swz(int r) { return (r ^ (r >> 2)) & 3; }

// ---------------------------------------------------------------------------
// Fused fp32 -> bf16 cast for hidden | W_qkv | W_out (contiguous bf16 dst)
// ---------------------------------------------------------------------------
#define N_HID ((size_t)Mq * Hq)          // 4194304
#define N_HW  (N_HID + (size_t)H3q * Hq) // 7340032
#define N_ALL (N_HW + (size_t)Hq * Hq)   // 8388608

__global__ __launch_bounds__(256) void cvt_all(
    const float* __restrict__ hidden, const float* __restrict__ wqkv,
    const float* __restrict__ wout, unsigned short* __restrict__ dst)
{
    size_t i = ((size_t)blockIdx.x * 256 + threadIdx.x) * 8;
    const float* src;
    if (i < N_HID)      src = hidden + i;
    else if (i < N_HW)  src = wqkv + (i - N_HID);
    else                src = wout + (i - N_HW);
    float4 a = *(const float4*)(src);
    float4 b = *(const float4*)(src + 4);
    union { unsigned int u[4]; ushortx8 s; } o;
    o.u[0] = pkbf(a.x, a.y); o.u[1] = pkbf(a.z, a.w);
    o.u[2] = pkbf(b.x, b.y); o.u[3] = pkbf(b.z, b.w);
    *(ushortx8*)(dst + i) = o.s;
}

// expmask[i] = 2^(mask[i]*log2e) = e^mask, bf16. 4096 elems, 2 blocks.
__global__ __launch_bounds__(256) void cvt_mask(
    const float* __restrict__ mask, unsigned short* __restrict__ em)
{
    int i = (blockIdx.x * 256 + threadIdx.x) * 8;
    union { unsigned int u[4]; ushortx8 s; } o;
    #pragma unroll
    for (int h = 0; h < 4; h++) {
        float a = exp2f(mask[i + 2*h]     * LOG2E);
        float b = exp2f(mask[i + 2*h + 1] * LOG2E);
        o.u[h] = pkbf(a, b);
    }
    *(ushortx8*)(em + i) = o.s;
}

// ---------------------------------------------------------------------------
// MFMA GEMM core: 128x128 tile, BK=32, 4 waves each computing 64x64.
// ---------------------------------------------------------------------------
#define TM 128
#define TN 128
#define TK 32

// GEMM1: -> qkv bf16 (Q scaled 1/8*log2e) + V'^T global [b,n,d,s] with
// e^mask folded into V' rows (so attention's PV carries the mask factor).
__global__ __launch_bounds__(256) void gemm_mfma_qkv(
    const unsigned short* __restrict__ A, const unsigned short* __restrict__ Bw,
    const float* __restrict__ bias, const float* __restrict__ mask,
    unsigned short* __restrict__ qkvC, unsigned short* __restrict__ vT,
    int M, int Nd, int K)
{
    __shared__ unsigned short As[TM][TK];
    __shared__ unsigned short Bs[TN][TK];

    const int tid = threadIdx.x;
    const int w = tid >> 6, lane = tid & 63;
    const int l15 = lane & 15, quad = lane >> 4;
    const int wr = (w & 1) * 64;
    const int wc = (w >> 1) * 64;
    const int row0 = blockIdx.y * TM;
    const int col0 = blockIdx.x * TN;

    const int srow16 = lane >> 2;
    const int sgd    = lane & 3;
    const int sgsrc  = (sgd ^ swz(srow16)) * 8;

    floatx4 acc[4][4];
    #pragma unroll
    for (int i = 0; i < 4; i++)
        #pragma unroll
        for (int j = 0; j < 4; j++) acc[i][j] = (floatx4){0.f,0.f,0.f,0.f};

    const int aswz = swz(l15) * 8;

    for (int k0 = 0; k0 < K; k0 += TK) {
        __syncthreads();
        #pragma unroll
        for (int c = 0; c < 2; c++) {
            int seg = w * 2 + c;
            int r = seg * 16 + srow16;
            gload16(A  + (size_t)(row0 + r) * K + k0 + sgsrc, &As[seg * 16][0]);
            gload16(Bw + (size_t)(col0 + r) * K + k0 + sgsrc, &Bs[seg * 16][0]);
        }
        __syncthreads();

        short8 af[4], bf[4];
        #pragma unroll
        for (int i = 0; i < 4; i++)
            af[i] = *(const short8*)&As[wr + i * 16 + l15][(quad * 8) ^ aswz];
        #pragma unroll
        for (int j = 0; j < 4; j++)
            bf[j] = *(const short8*)&Bs[wc + j * 16 + l15][(quad * 8) ^ aswz];
        #pragma unroll
        for (int i = 0; i < 4; i++)
            #pragma unroll
            for (int j = 0; j < 4; j++)
                acc[i][j] = __builtin_amdgcn_mfma_f32_16x16x32_bf16(af[i], bf[j], acc[i][j], 0, 0, 0);
    }

    const bool isV = (col0 >= 2 * Hq);   // uniform per block (128 | 2048)

    #pragma unroll
    for (int i = 0; i < 4; i++) {
        const int rb = row0 + wr + i * 16 + quad * 4;
        const int b  = rb >> 11;
        const int s  = rb & (Sq - 1);
        float expm[4];
        if (isV) {
            #pragma unroll
            for (int rr = 0; rr < 4; rr++)
                expm[rr] = exp2f(mask[(size_t)b * Sq + s + rr] * LOG2E);
        }
        #pragma unroll
        for (int j = 0; j < 4; j++) {
            const int c = col0 + wc + j * 16 + l15;
            const float bia = bias[c];
            if (!isV) {
                // Q columns: fold 1/sqrt(64) and log2(e) for exp2-softmax
                const float scale = (c < Hq) ? (0.125f * LOG2E) : 1.0f;
                #pragma unroll
                for (int rr = 0; rr < 4; rr++)
                    qkvC[(size_t)(rb + rr) * Nd + c] = f2bf((acc[i][j][rr] + bia) * scale);
            } else {
                const int c2 = c - 2 * Hq;           // n*64+d
                ushortx4 o;
                #pragma unroll
                for (int rr = 0; rr < 4; rr++)
                    o[rr] = f2bf((acc[i][j][rr] + bia) * expm[rr]);
                *(ushortx4*)&vT[((size_t)(b << 10) + c2) * Sq + s] = o;
            }
        }
    }
}

// GEMM2: x = A*Bw^T + bias + residual -> bf16 (LN reads bf16, stats in fp32)
__global__ __launch_bounds__(256) void gemm_mfma_out(
    const unsigned short* __restrict__ A, const unsigned short* __restrict__ Bw,
    const float* __restrict__ bias, const float* __restrict__ res,
    unsigned short* __restrict__ X, int M, int Nd, int K)
{
    __shared__ unsigned short As[TM][TK];
    __shared__ unsigned short Bs[TN][TK];

    const int tid = threadIdx.x;
    const int w = tid >> 6, lane = tid & 63;
    const int l15 = lane & 15, quad = lane >> 4;
    const int wr = (w & 1) * 64;
    const int wc = (w >> 1) * 64;
    const int row0 = blockIdx.y * TM;
    const int col0 = blockIdx.x * TN;

    const int srow16 = lane >> 2;
    const int sgd    = lane & 3;
    const int sgsrc  = (sgd ^ swz(srow16)) * 8;

    floatx4 acc[4][4];
    #pragma unroll
    for (int i = 0; i < 4; i++)
        #pragma unroll
        for (int j = 0; j < 4; j++) acc[i][j] = (floatx4){0.f,0.f,0.f,0.f};

    const int aswz = swz(l15) * 8;

    for (int k0 = 0; k0 < K; k0 += TK) {
        __syncthreads();
        #pragma unroll
        for (int c = 0; c < 2; c++) {
            int seg = w * 2 + c;
            int r = seg * 16 + srow16;
            gload16(A  + (size_t)(row0 + r) * K + k0 + sgsrc, &As[seg * 16][0]);
            gload16(Bw + (size_t)(col0 + r) * K + k0 + sgsrc, &Bs[seg * 16][0]);
        }
        __syncthreads();

        short8 af[4], bf[4];
        #pragma unroll
        for (int i = 0; i < 4; i++)
            af[i] = *(const short8*)&As[wr + i * 16 + l15][(quad * 8) ^ aswz];
        #pragma unroll
        for (int j = 0; j < 4; j++)
            bf[j] = *(const short8*)&Bs[wc + j * 16 + l15][(quad * 8) ^ aswz];
        #pragma unroll
        for (int i = 0; i < 4; i++)
            #pragma unroll
            for (int j = 0; j < 4; j++)
                acc[i][j] = __builtin_amdgcn_mfma_f32_16x16x32_bf16(af[i], bf[j], acc[i][j], 0, 0, 0);
    }

    #pragma unroll
    for (int i = 0; i < 4; i++) {
        const int rb = row0 + wr + i * 16 + quad * 4;
        #pragma unroll
        for (int j = 0; j < 4; j++) {
            const int c = col0 + wc + j * 16 + l15;
            const float bia = bias[c];
            #pragma unroll
            for (int rr = 0; rr < 4; rr++) {
                X[(size_t)(rb + rr) * Nd + c] =
                    f2bf(acc[i][j][rr] + bia + res[(size_t)(rb + rr) * Nd + c]);
            }
        }
    }
}

// ---------------------------------------------------------------------------
// Grid-split-K MFMA flash attention, 32 q/wave (2 subtiles), z-split x2.
// VALU-diet softmax: p = exp2(s) only (Q carries 0.125*log2e; e^mask folded
// into V' at GEMM1). l computed ON THE MFMA PIPE: lacc += mfma(mf, pf) where
// mf is an A-fragment of 2^(m_k*log2e) (bf16, broadcast ds_read_b64) — every
// row of lacc equals l_q, so the epilogue needs no shuffles. Per-lane per-tile
// softmax VALU: 48 ops (was 112). K via global_load_lds w/ source-address
// swizzle; V register-staged; no min-waves clause (spill-free, ~100 VGPR).
// ---------------------------------------------------------------------------
#define KTILES 16   // 64-key tiles per z-half

__global__ __launch_bounds__(256) void attn_mfma(
    const unsigned short* __restrict__ qkv, const unsigned short* __restrict__ vT,
    const unsigned short* __restrict__ expmask, unsigned short* __restrict__ Opart,
    float* __restrict__ Lpart)
{
    __shared__ unsigned short Ks[64][64];   // [key][d], src-granule swizzled
    __shared__ unsigned short Vt[64][64];   // [d][key], granule-XOR swizzled
    __shared__ unsigned short maskE[64];    // 2^(m_k*log2e), bf16

    const int tid  = threadIdx.x;
    const int w    = tid >> 6;
    const int lane = tid & 63;
    const int l15  = lane & 15;
    const int quad = lane >> 4;

    const int qtile = blockIdx.x;     // 0..15 (128 queries each)
    const int bn    = blockIdx.y;
    const int z     = blockIdx.z;
    const int n     = bn & 15;
    const int b     = bn >> 4;

    const int qoff = n * HNq;
    const int koff = Hq + n * HNq;
    const int kbase = z * (KTILES * 64);

    // Q B-fragments for both subtiles (n=l15 -> query row, k=quad*8+j)
    short8 qfrag0[2], qfrag1[2];
    {
        const int qrow0 = qtile * 128 + w * 16 + l15;
        const unsigned short* qp = qkv + (size_t)(b * Sq + qrow0) * H3q + qoff + quad * 8;
        qfrag0[0] = *(const short8*)(qp);
        qfrag0[1] = *(const short8*)(qp + 32);
        qp += (size_t)64 * H3q;
        qfrag1[0] = *(const short8*)(qp);
        qfrag1[1] = *(const short8*)(qp + 32);
    }

    floatx4 oacc0[4], oacc1[4];   // O^T per subtile: d = dt*16+quad*4+r, q=l15
    #pragma unroll
    for (int dt = 0; dt < 4; dt++) {
        oacc0[dt] = (floatx4){0.f,0.f,0.f,0.f};
        oacc1[dt] = (floatx4){0.f,0.f,0.f,0.f};
    }
    floatx4 lacc0 = (floatx4){0.f,0.f,0.f,0.f};
    floatx4 lacc1 = (floatx4){0.f,0.f,0.f,0.f};

    // K DMA geometry: wave w stages rows w*16..w*16+15 via 2 global_load_lds.
    const int krow8 = lane >> 3;               // 0..7
    const int kgr   = (lane & 7) ^ (krow8 & 7);
    const unsigned short* kp0 = qkv + (size_t)(b * Sq + kbase + w * 16 + krow8) * H3q + koff + kgr * 8;
    const unsigned short* kp1 = kp0 + (size_t)8 * H3q;
    unsigned short* kd0 = &Ks[w * 16][0];
    unsigned short* kd1 = &Ks[w * 16 + 8][0];
    const size_t kstep = (size_t)64 * H3q;

    // V staging geometry (granule-XOR swizzle by d&7)
    const int vd0 = tid >> 3,        vg0 = tid & 7;
    const int vd1 = 32 + (tid >> 3), vg1 = tid & 7;
    const unsigned short* vbase = vT + (size_t)(b * Nq + n) * HNq * Sq;
    const unsigned short* ebase = expmask + (size_t)b * Sq;

    // preload V/expmask registers for tile 0
    ushortx8 vreg0, vreg1;
    ushortx4 ereg;
    {
        vreg0 = *(const ushortx8*)(vbase + (size_t)vd0 * Sq + kbase + vg0 * 8);
        vreg1 = *(const ushortx8*)(vbase + (size_t)vd1 * Sq + kbase + vg1 * 8);
        if (tid < 16) ereg = *(const ushortx4*)(ebase + kbase + tid * 4);
    }

    for (int kt = 0; kt < KTILES; kt++) {
        __syncthreads();   // previous tile fully consumed
        // async K DMA for this tile + store V/expmask regs
        gload16(kp0, kd0);
        gload16(kp1, kd1);
        kp0 += kstep; kp1 += kstep;
        *(ushortx8*)&Vt[vd0][(vg0 ^ (vd0 & 7)) * 8] = vreg0;
        *(ushortx8*)&Vt[vd1][(vg1 ^ (vd1 & 7)) * 8] = vreg1;
        if (tid < 16) *(ushortx4*)&maskE[tid * 4] = ereg;
        __syncthreads();   // implicit vmcnt(0): K DMA landed, stores visible

        // prefetch V/expmask for next tile
        if (kt + 1 < KTILES) {
            const int nk0 = kbase + (kt + 1) * 64;
            vreg0 = *(const ushortx8*)(vbase + (size_t)vd0 * Sq + nk0 + vg0 * 8);
            vreg1 = *(const ushortx8*)(vbase + (size_t)vd1 * Sq + nk0 + vg1 * 8);
            if (tid < 16) ereg = *(const ushortx4*)(ebase + nk0 + tid * 4);
        }

        // ---- S^T = K Q^T for both subtiles; each af read feeds 2 MFMAs
        floatx4 sacc0[4], sacc1[4];
        #pragma unroll
        for (int ct = 0; ct < 4; ct++) {
            sacc0[ct] = (floatx4){0.f,0.f,0.f,0.f};
            sacc1[ct] = (floatx4){0.f,0.f,0.f,0.f};
        }
        #pragma unroll
        for (int ks = 0; ks < 2; ks++) {
            #pragma unroll
            for (int ct = 0; ct < 4; ct++) {
                short8 af = *(const short8*)&Ks[ct * 16 + l15][((4 * ks + quad) ^ (l15 & 7)) * 8];
                sacc0[ct] = __builtin_amdgcn_mfma_f32_16x16x32_bf16(af, qfrag0[ks], sacc0[ct], 0, 0, 0);
                sacc1[ct] = __builtin_amdgcn_mfma_f32_16x16x32_bf16(af, qfrag1[ks], sacc1[ct], 0, 0, 0);
            }
        }

        // ---- exp2-only softmax (mask in V'/mf; l via MFMA below)
        short8 pf0[2], pf1[2];   // pf[ks][(ct&1)*4+r] = P(key=16ct+4quad+r)
        #pragma unroll
        for (int ks = 0; ks < 2; ks++) {
            union { unsigned int u[4]; short8 s; } pk;
            #pragma unroll
            for (int h = 0; h < 2; h++) {
                const int ct = ks * 2 + h;
                pk.u[h * 2]     = pkbf(exp2f(sacc0[ct][0]), exp2f(sacc0[ct][1]));
                pk.u[h * 2 + 1] = pkbf(exp2f(sacc0[ct][2]), exp2f(sacc0[ct][3]));
            }
            pf0[ks] = pk.s;
        }
        #pragma unroll
        for (int ks = 0; ks < 2; ks++) {
            union { unsigned int u[4]; short8 s; } pk;
            #pragma unroll
            for (int h = 0; h < 2; h++) {
                const int ct = ks * 2 + h;
                pk.u[h * 2]     = pkbf(exp2f(sacc1[ct][0]), exp2f(sacc1[ct][1]));
                pk.u[h * 2 + 1] = pkbf(exp2f(sacc1[ct][2]), exp2f(sacc1[ct][3]));
            }
            pf1[ks] = pk.s;
        }

        // ---- l via MFMA: mf A-frag = 2^(m_k) in the SAME permuted k-slots
        // as pf: slot quad*8+j <-> key 16(2ks+(j>=4)) + 4quad + (j%4).
        // Broadcast ds_read_b64 (address depends on quad,ks only).
        #pragma unroll
        for (int ks = 0; ks < 2; ks++) {
            short4s mlo = *(const short4s*)&maskE[32 * ks + quad * 4];
            short4s mhi = *(const short4s*)&maskE[32 * ks + 16 + quad * 4];
            short8 mf = __builtin_shufflevector(mlo, mhi, 0, 1, 2, 3, 4, 5, 6, 7);
            lacc0 = __builtin_amdgcn_mfma_f32_16x16x32_bf16(mf, pf0[ks], lacc0, 0, 0, 0);
            lacc1 = __builtin_amdgcn_mfma_f32_16x16x32_bf16(mf, pf1[ks], lacc1, 0, 0, 0);
        }

        // ---- O^T += V'^T P^T; each vf read feeds 2 MFMAs
        #pragma unroll
        for (int ks = 0; ks < 2; ks++) {
            const int c0 = (((4 * ks +     (quad >> 1)) ^ (l15 & 7)) * 8) + (quad & 1) * 4;
            const int c1 = (((4 * ks + 2 + (quad >> 1)) ^ (l15 & 7)) * 8) + (quad & 1) * 4;
            #pragma unroll
            for (int dt = 0; dt < 4; dt++) {
                const int d = dt * 16 + l15;
                short4s lo = *(const short4s*)&Vt[d][c0];
                short4s hi = *(const short4s*)&Vt[d][c1];
                short8 vf = __builtin_shufflevector(lo, hi, 0, 1, 2, 3, 4, 5, 6, 7);
                oacc0[dt] = __builtin_amdgcn_mfma_f32_16x16x32_bf16(vf, pf0[ks], oacc0[dt], 0, 0, 0);
                oacc1[dt] = __builtin_amdgcn_mfma_f32_16x16x32_bf16(vf, pf1[ks], oacc1[dt], 0, 0, 0);
            }
        }
    }

    // ---- epilogue: un-normalized partial O (bf16) + per-query l (no shfls:
    // every row of lacc holds l_q for q=l15)
    unsigned short* Ow = Opart + (size_t)z * Mq * Hq;
    #pragma unroll
    for (int sub = 0; sub < 2; sub++) {
        const float l_i = sub ? lacc1[0] : lacc0[0];
        const int qrow = qtile * 128 + sub * 64 + w * 16 + l15;
        if (quad == 0)
            Lpart[(size_t)z * Mq * Nq + (size_t)(b * Sq + qrow) * Nq + n] = l_i;
        #pragma unroll
        for (int dt = 0; dt < 4; dt++) {
            const floatx4 oa = sub ? oacc1[dt] : oacc0[dt];
            union { unsigned int u[2]; ushortx4 s; } o;
            o.u[0] = pkbf(oa[0], oa[1]);
            o.u[1] = pkbf(oa[2], oa[3]);
            const int col = n * HNq + dt * 16 + quad * 4;
            *(ushortx4*)&Ow[(size_t)(b * Sq + qrow) * Hq + col] = o.s;
        }
    }
}

// ---------------------------------------------------------------------------
// Merge the two split-K halves: ctx = (O0 + O1) / (l0 + l1), bf16 out.
// ---------------------------------------------------------------------------
__global__ __launch_bounds__(256) void attn_merge(
    const unsigned short* __restrict__ Opart, const float* __restrict__ Lpart,
    unsigned short* __restrict__ ctx)
{
    const size_t idx = ((size_t)blockIdx.x * 256 + threadIdx.x) * 4;
    const int row = (int)(idx >> 10);          // b*Sq + s
    const int n   = ((int)idx >> 6) & 15;
    const float l = Lpart[(size_t)row * Nq + n]
                  + Lpart[(size_t)Mq * Nq + (size_t)row * Nq + n];
    const float inv = 1.0f / l;
    ushortx4 a = *(const ushortx4*)(Opart + idx);
    ushortx4 c = *(const ushortx4*)(Opart + (size_t)Mq * Hq + idx);
    union { unsigned int u[2]; ushortx4 s; } o;
    o.u[0] = pkbf((bf2f(a[0]) + bf2f(c[0])) * inv, (bf2f(a[1]) + bf2f(c[1])) * inv);
    o.u[1] = pkbf((bf2f(a[2]) + bf2f(c[2])) * inv, (bf2f(a[3]) + bf2f(c[3])) * inv);
    *(ushortx4*)(ctx + idx) = o.s;
}

// ---------------------------------------------------------------------------
// Row LayerNorm over H=1024, bf16 input, fp32 stats, fp32 output.
// ---------------------------------------------------------------------------
__global__ __launch_bounds__(256) void ln_kernel(
    const unsigned short* __restrict__ X, const float* __restrict__ gamma,
    const float* __restrict__ beta, float* __restrict__ out)
{
    const int row = blockIdx.x;
    const int c0  = threadIdx.x * 4;
    ushortx4 xv = *(const ushortx4*)(X + (size_t)row * Hq + c0);
    float vals[4];
    float lsum = 0.0f;
    #pragma unroll
    for (int i = 0; i < 4; i++) { vals[i] = bf2f(xv[i]); lsum += vals[i]; }

    __shared__ float red[8];
    const int wid = threadIdx.x >> 6, lane = threadIdx.x & 63;

    float s = lsum;
    #pragma unroll
    for (int off = 32; off >= 1; off >>= 1) s += __shfl_xor(s, off, 64);
    if (lane == 0) red[wid] = s;
    __syncthreads();
    const float mean = (red[0] + red[1] + red[2] + red[3]) * (1.0f / Hq);

    float v = 0.0f;
    #pragma unroll
    for (int i = 0; i < 4; i++) { float d = vals[i] - mean; v += d * d; }
    #pragma unroll
    for (int off = 32; off >= 1; off >>= 1) v += __shfl_xor(v, off, 64);
    if (lane == 0) red[4 + wid] = v;
    __syncthreads();
    const float var  = (red[4] + red[5] + red[6] + red[7]) * (1.0f / Hq);
    const float rstd = rsqrtf(var + 1e-12f);

    float4 gm = *(const float4*)(gamma + c0);
    float4 bt = *(const float4*)(beta + c0);
    float4 o;
    o.x = (vals[0] - mean) * rstd * gm.x + bt.x;
    o.y = (vals[1] - mean) * rstd * gm.y + bt.y;
    o.z = (vals[2] - mean) * rstd * gm.z + bt.z;
    o.w = (vals[3] - mean) * rstd * gm.w + bt.w;
    *(float4*)(out + (size_t)row * Hq + c0) = o;
}

// ---------------------------------------------------------------------------
extern "C" void kernel_launch(void* const* d_in, const int* in_sizes, int n_in,
                              void* d_out, int out_size, void* d_ws, size_t ws_size,
                              hipStream_t stream)
{
    const float* hidden = (const float*)d_in[0];
    const float* mask   = (const float*)d_in[1];
    const float* W_qkv  = (const float*)d_in[2];
    const float* b_qkv  = (const float*)d_in[3];
    const float* W_out  = (const float*)d_in[4];
    const float* b_out  = (const float*)d_in[5];
    const float* gamma  = (const float*)d_in[6];
    const float* beta   = (const float*)d_in[7];
    float* out = (float*)d_out;

    const size_t nHid  = (size_t)Mq * Hq;        // 4 M
    const size_t nWq   = (size_t)H3q * Hq;       // 3 M
    const size_t nWo   = (size_t)Hq * Hq;        // 1 M
    const size_t nQKV  = (size_t)Mq * H3q;       // 12 M
    const size_t nVT   = (size_t)Bq * Hq * Sq;   // 4 M
    const size_t nCtx  = (size_t)Mq * Hq;        // 4 M

    unsigned short* hidden_bf = (unsigned short*)d_ws;
    unsigned short* Wqkv_bf   = hidden_bf + nHid;
    unsigned short* Wout_bf   = Wqkv_bf + nWq;
    unsigned short* qkv_bf    = Wout_bf + nWo;
    unsigned short* vT        = qkv_bf + nQKV;
    unsigned short* ctx_bf    = vT + nVT;
    unsigned short* x_bf      = ctx_bf + nCtx;
    unsigned short* opart     = x_bf + nHid;           // 2 * 4M bf16 = 16 MB
    float*          lpart     = (float*)(opart + 2 * nHid);  // 2*64K floats
    unsigned short* expm_bf   = (unsigned short*)(lpart + 2 * (size_t)Mq * Nq);

    dim3 blk(256);

    // 0) fused fp32 -> bf16 cast + expmask precompute
    cvt_all<<<dim3((int)(N_ALL / 2048)), blk, 0, stream>>>(
        hidden, W_qkv, W_out, hidden_bf);
    cvt_mask<<<dim3(2), blk, 0, stream>>>(mask, expm_bf);

    // 1) QKV projection (MFMA) -> qkv bf16 (Q/K) + V'^T (e^mask folded)
    gemm_mfma_qkv<<<dim3(H3q / TN, Mq / TM), blk, 0, stream>>>(
        hidden_bf, Wqkv_bf, b_qkv, mask, qkv_bf, vT, Mq, H3q, Hq);

    // 2) Grid-split-K MFMA flash attention (32 q/wave) -> partial O/l
    attn_mfma<<<dim3(Sq / 128, Bq * Nq, 2), blk, 0, stream>>>(
        qkv_bf, vT, expm_bf, opart, lpart);

    // 2b) merge halves -> ctx bf16
    attn_merge<<<dim3((int)(nCtx / 1024)), blk, 0, stream>>>(
        opart, lpart, ctx_bf);

    // 3) Output projection (MFMA) + bias + residual -> x bf16
    gemm_mfma_out<<<dim3(Hq / TN, Mq / TM), blk, 0, stream>>>(
        ctx_bf, Wout_bf, b_out, hidden, x_bf, Mq, Hq, Hq);

    // 4) LayerNorm: bf16 x -> fp32 out
    ln_kernel<<<dim3(Mq), blk, 0, stream>>>(x_bf, gamma, beta, out);
}